// Round 8
// baseline (109.286 us; speedup 1.0000x reference)
//
#include <hip/hip_runtime.h>
#include <hip/hip_bf16.h>
#include <math.h>

#define BT 8192      // B*T rows total
#define TT 2048      // T
#define DM 1024      // d_model
#define DK 128       // dk == dv
#define NBLK 65      // split-K blocks per batch (sum of S over 16 q-blocks)

typedef __bf16 bf16x8 __attribute__((ext_vector_type(8)));
typedef float  f32x4  __attribute__((ext_vector_type(4)));
typedef unsigned short ushort4v __attribute__((ext_vector_type(4)));
typedef unsigned short ushort8v __attribute__((ext_vector_type(8)));

static __device__ __forceinline__ unsigned short f2bf(float x) {
    union { float f; unsigned u; } v; v.f = x;
    unsigned r = v.u + 0x7fffu + ((v.u >> 16) & 1u);   // RNE
    return (unsigned short)(r >> 16);
}
static __device__ __forceinline__ float bf2f(unsigned short u) {
    union { unsigned u; float f; } v; v.u = (unsigned)u << 16;
    return v.f;
}

// slices for q-block index q (0..15):  S = max(1, (q+1)>>1)   (sum = 65)
__host__ __device__ constexpr int slc_of(int q) { return (q == 0) ? 1 : ((q + 1) >> 1); }
__host__ __device__ constexpr int pfx_of(int q) { return (q == 0) ? 0 : 1 + (q * q - (q & 1)) / 4; }

// 1/sqrt(128) * log2(e): QK^T computed directly in log2 domain
#define QSCALE 0.1275312772629451f

// ---------------------------------------------------------------------------
// Prep: Wt[z][n][k] = bf16(W_z[k][n])
// ---------------------------------------------------------------------------
__global__ __launch_bounds__(256) void wt_prep(
    const float* __restrict__ Wq, const float* __restrict__ Wk,
    const float* __restrict__ Wv, unsigned short* __restrict__ Wt)
{
    const int z = blockIdx.y;
    const float* __restrict__ W = (z == 0) ? Wq : (z == 1 ? Wk : Wv);
    const int k0 = blockIdx.x * 64;

    __shared__ __align__(16) __bf16 T[128][72];
    const int t = threadIdx.x;

#pragma unroll
    for (int jj = 0; jj < 8; ++jj) {
        int c  = jj * 256 + t;
        int k  = c >> 5;
        int n4 = (c & 31) * 4;
        float4 f = *reinterpret_cast<const float4*>(&W[(size_t)(k0 + k) * DK + n4]);
        T[n4 + 0][k] = (__bf16)f.x;
        T[n4 + 1][k] = (__bf16)f.y;
        T[n4 + 2][k] = (__bf16)f.z;
        T[n4 + 3][k] = (__bf16)f.w;
    }
    __syncthreads();

    const int n  = t >> 1;
    const int cb = (t & 1) * 32;
#pragma unroll
    for (int jj = 0; jj < 4; ++jj) {
        *reinterpret_cast<ushort8v*>(&Wt[((size_t)z * DK + n) * DM + k0 + cb + jj * 8]) =
            *reinterpret_cast<const ushort8v*>(&T[n][cb + jj * 8]);
    }
}

// ---------------------------------------------------------------------------
// Projection via MFMA, v3 (r8): NO LDS, NO BARRIERS.
// W (bf16, pre-transposed, 768 KB total) is L2-resident; each lane loads its
// B-fragments straight from global and its own X row fragment (fp32->bf16 in
// reg). Full unroll over 16 K-iters; the scheduler overlaps next-iter loads
// under current MFMAs and waves drift freely (no lockstep to drain vmcnt).
// Tile 64x128 per block, 4 waves (wave = 16 rows x 128 cols).
// ---------------------------------------------------------------------------
__global__ __launch_bounds__(256) void proj_mfma(
    const float* __restrict__ XQ, const float* __restrict__ XKV,
    const unsigned short* __restrict__ Wt,
    const float* __restrict__ bq, const float* __restrict__ bk,
    const float* __restrict__ bv,
    unsigned short* __restrict__ Qb, unsigned short* __restrict__ Kb,
    unsigned short* __restrict__ Vt)
{
    const int z = blockIdx.y;
    const float* __restrict__ X    = (z == 0) ? XQ : XKV;
    const float* __restrict__ bias = (z == 0) ? bq : (z == 1 ? bk : bv);
    const unsigned short* __restrict__ Wz = Wt + (size_t)z * DK * DM;

    const int t    = threadIdx.x;
    const int lane = t & 63;
    const int wv   = t >> 6;
    const int i16  = lane & 15;
    const int g    = lane >> 4;
    const int m0   = blockIdx.x * 64;

    // lane-private operand base pointers
    const float* __restrict__ Xrow =
        X + (size_t)(m0 + wv * 16 + i16) * DM + g * 8;
    const unsigned short* __restrict__ Wrow =
        Wz + (size_t)i16 * DM + g * 8;

    f32x4 acc[8];
#pragma unroll
    for (int nt = 0; nt < 8; ++nt) acc[nt] = (f32x4){0.f, 0.f, 0.f, 0.f};

#pragma unroll
    for (int k0 = 0; k0 < DM; k0 += 64) {
        // X fragment: 4 x float4 (this lane's own row, 2 c-groups)
        float4 xr[4];
#pragma unroll
        for (int c = 0; c < 2; ++c)
#pragma unroll
            for (int h = 0; h < 2; ++h)
                xr[c * 2 + h] = *reinterpret_cast<const float4*>(
                    &Xrow[k0 + c * 32 + h * 4]);

        // W fragments: 16 x bf16x8 straight from L2
        bf16x8 wf[16];
#pragma unroll
        for (int c = 0; c < 2; ++c)
#pragma unroll
            for (int nt = 0; nt < 8; ++nt)
                wf[c * 8 + nt] = *reinterpret_cast<const bf16x8*>(
                    &Wrow[(size_t)nt * 16 * DM + k0 + c * 32]);

#pragma unroll
        for (int c = 0; c < 2; ++c) {
            union { __bf16 b[8]; bf16x8 v; } u;
            u.b[0] = (__bf16)xr[c * 2].x;     u.b[1] = (__bf16)xr[c * 2].y;
            u.b[2] = (__bf16)xr[c * 2].z;     u.b[3] = (__bf16)xr[c * 2].w;
            u.b[4] = (__bf16)xr[c * 2 + 1].x; u.b[5] = (__bf16)xr[c * 2 + 1].y;
            u.b[6] = (__bf16)xr[c * 2 + 1].z; u.b[7] = (__bf16)xr[c * 2 + 1].w;
#pragma unroll
            for (int nt = 0; nt < 8; ++nt)
                acc[nt] = __builtin_amdgcn_mfma_f32_16x16x32_bf16(
                    u.v, wf[c * 8 + nt], acc[nt], 0, 0, 0);
        }
    }

    if (z == 0) {
#pragma unroll
        for (int nt = 0; nt < 8; ++nt) {
            int n = nt * 16 + i16;
            float bb = bias[n];
#pragma unroll
            for (int r = 0; r < 4; ++r) {
                int mrow = m0 + wv * 16 + g * 4 + r;
                Qb[(size_t)mrow * DK + n] = f2bf((acc[nt][r] + bb) * QSCALE);
            }
        }
    } else if (z == 1) {
#pragma unroll
        for (int nt = 0; nt < 8; ++nt) {
            int n = nt * 16 + i16;
            float bb = bias[n];
#pragma unroll
            for (int r = 0; r < 4; ++r) {
                int mrow = m0 + wv * 16 + g * 4 + r;
                Kb[(size_t)mrow * DK + n] = f2bf(acc[nt][r] + bb);
            }
        }
    } else {
        const int b  = m0 / TT;
        const int t0 = (m0 % TT) + wv * 16 + g * 4;
#pragma unroll
        for (int nt = 0; nt < 8; ++nt) {
            int d = nt * 16 + i16;
            float bb = bias[d];
            ushort4v r;
#pragma unroll
            for (int e = 0; e < 4; ++e) r[e] = f2bf(acc[nt][e] + bb);
            *reinterpret_cast<ushort4v*>(&Vt[((size_t)b * DK + d) * TT + t0]) = r;
        }
    }
}

// ---------------------------------------------------------------------------
// LDS-staged flash attention, proportional split-K (unchanged from r6).
// ---------------------------------------------------------------------------
__global__ __launch_bounds__(512, 2) void attn_kernel(
    const unsigned short* __restrict__ Qb, const unsigned short* __restrict__ Kb,
    const unsigned short* __restrict__ Vt,
    unsigned short* __restrict__ pO, float* __restrict__ pMS)
{
    __shared__ __align__(16) unsigned short lds_[2][16384];   // [buf][K 8192 | V 8192]

    const int t    = threadIdx.x;
    const int lane = t & 63;
    const int w    = t >> 6;
    const int qi   = lane & 15;
    const int g    = lane >> 4;

    // ---- decode block -> (batch, q-block, slice)
    const int bi    = blockIdx.x;
    const int batch = bi / NBLK;
    const int rr    = bi - batch * NBLK;
    int qbl = 0;
#pragma unroll
    for (int i = 1; i < 16; ++i) if (rr >= pfx_of(i)) qbl = i;
    const int slice = rr - (qbl == 0 ? 0 : 1 + (qbl * qbl - (qbl & 1)) / 4);
    const int S     = (qbl == 0) ? 1 : ((qbl + 1) >> 1);
    const int nch   = 2 * qbl + 2;            // 64-key chunks this q-block needs
    const int q0    = qbl * 128;              // batch-local first q row

    const unsigned short* __restrict__ Kbb = Kb + (size_t)batch * TT * DK;
    const unsigned short* __restrict__ Vtb = Vt + (size_t)batch * DK * TT;

    const int qrow  = q0 + w * 16 + qi;       // this lane's q (batch-local)
    const int qminw = q0 + w * 16;            // wave's min q row
    const int qmaxw = q0 + w * 16 + 15;       // wave's max q row

    bf16x8 qf[4];
#pragma unroll
    for (int c = 0; c < 4; ++c)
        qf[c] = *reinterpret_cast<const bf16x8*>(
            &Qb[((size_t)batch * TT + qrow) * DK + c * 32 + g * 8]);

    f32x4 accO[8];
#pragma unroll
    for (int dt = 0; dt < 8; ++dt) accO[dt] = (f32x4){0.f, 0.f, 0.f, 0.f};
    float m = -1e30f, s = 0.f;                // s lane-local, reduced at end

    // ---- staging helpers (wave w<4: K rows, w>=4: Vt rows), 4x16B per lane
    ushort8v sreg[4];
    const int kslot0 = (w & 3) * 256;

#define STAGE_ISSUE(c_)                                                         \
    {                                                                           \
        const int k0s = (c_) * 64;                                              \
        if (w < 4) {                                                            \
            _Pragma("unroll")                                                   \
            for (int i = 0; i < 4; ++i) {                                       \
                int slot = kslot0 + i * 64 + lane;                              \
                int row  = slot >> 4;                                           \
                int colg = (slot & 15) ^ (row & 15);                            \
                sreg[i] = *reinterpret_cast<const ushort8v*>(                   \
                    &Kbb[(size_t)(k0s + row) * DK + colg * 8]);                 \
            }                                                                   \
        } else {                                                                \
            _Pragma("unroll")                                                   \
            for (int i = 0; i < 4; ++i) {                                       \
                int slot = kslot0 + i * 64 + lane;                              \
                int row  = slot >> 3;                                           \
                int colg = (slot & 7) ^ (row & 7);                              \
                sreg[i] = *reinterpret_cast<const ushort8v*>(                   \
                    &Vtb[(size_t)row * TT + k0s + colg * 8]);                   \
            }                                                                   \
        }                                                                       \
    }

#define STAGE_WRITE(buf_)                                                       \
    {                                                                           \
        const int base = (w < 4) ? 0 : 8192;                                    \
        _Pragma("unroll")                                                       \
        for (int i = 0; i < 4; ++i) {                                           \
            int slot = kslot0 + i * 64 + lane;                                  \
            *reinterpret_cast<ushort8v*>(&lds_[buf_][base + slot * 8]) = sreg[i]; \
        }                                                                       \
    }

    // prologue: stage first chunk into buf 0
    STAGE_ISSUE(slice);
    STAGE_WRITE(0);
    __syncthreads();

    int buf = 0;
    for (int c = slice; c < nch; c += S) {
        const int cn = c + S;
        if (cn < nch) STAGE_ISSUE(cn);

        const int k0 = c * 64;
        if (k0 <= qmaxw) {
            // ---- QK^T (S^T): lane(qi,g) col=qi, rows k0+ks*16+g*4+r
            f32x4 accS[4];
#pragma unroll
            for (int ks = 0; ks < 4; ++ks) accS[ks] = (f32x4){0.f, 0.f, 0.f, 0.f};
#pragma unroll
            for (int cc = 0; cc < 4; ++cc) {
#pragma unroll
                for (int ks = 0; ks < 4; ++ks) {
                    bf16x8 kf = *reinterpret_cast<const bf16x8*>(
                        &lds_[buf][(ks * 16 + qi) * 128 + ((cc * 4 + g) ^ qi) * 8]);
                    accS[ks] = __builtin_amdgcn_mfma_f32_16x16x32_bf16(kf, qf[cc], accS[ks], 0, 0, 0);
                }
            }

            // ---- mask + local max (log2 domain already)
            // mask needed unless ALL 64 keys are <= the wave's MIN row
            float xmax = -1e30f;
            if (k0 + 63 > qminw) {
#pragma unroll
                for (int ks = 0; ks < 4; ++ks)
#pragma unroll
                    for (int r = 0; r < 4; ++r) {
                        int k = k0 + ks * 16 + g * 4 + r;
                        float v0 = (k <= qrow) ? accS[ks][r] : -1e30f;
                        accS[ks][r] = v0;
                        xmax = fmaxf(xmax, v0);
                    }
            } else {
#pragma unroll
                for (int ks = 0; ks < 4; ++ks)
#pragma unroll
                    for (int r = 0; r < 4; ++r) xmax = fmaxf(xmax, accS[ks][r]);
            }

            // ---- defer-max
            if (__any(xmax > m + 8.f)) {
                xmax = fmaxf(xmax, __shfl_xor(xmax, 16));
                xmax = fmaxf(xmax, __shfl_xor(xmax, 32));
                float mn   = fmaxf(m, xmax);
                float corr = __builtin_amdgcn_exp2f(m - mn);
                s *= corr;
#pragma unroll
                for (int dt = 0; dt < 8; ++dt)
#pragma unroll
                    for (int e = 0; e < 4; ++e) accO[dt][e] *= corr;
                m = mn;
            }

            // ---- exp2 + pack pairs: pk[ks*2+h] = (p(r=2h), p(r=2h+1))
            unsigned pk[8];
#pragma unroll
            for (int ks = 0; ks < 4; ++ks)
#pragma unroll
                for (int h = 0; h < 2; ++h) {
                    float plo = __builtin_amdgcn_exp2f(accS[ks][h * 2]     - m);
                    float phi = __builtin_amdgcn_exp2f(accS[ks][h * 2 + 1] - m);
                    s += plo + phi;
                    pk[ks * 2 + h] = (unsigned)f2bf(plo) | ((unsigned)f2bf(phi) << 16);
                }

            // ---- redistribute S^T -> PV B-fragments (16 shuffles)
            const int srcl0 = qi + 32 * (g & 1);
            bf16x8 pf[2];
#pragma unroll
            for (int c2 = 0; c2 < 2; ++c2) {
                union { unsigned u[4]; bf16x8 v; } pu;
#pragma unroll
                for (int w4 = 0; w4 < 4; ++w4) {
                    int srcl = srcl0 + 16 * (w4 >> 1);
                    int a = __shfl((int)pk[c2 * 4 + (w4 & 1)],     srcl);
                    int b = __shfl((int)pk[c2 * 4 + 2 + (w4 & 1)], srcl);
                    pu.u[w4] = (g & 2) ? (unsigned)b : (unsigned)a;
                }
                pf[c2] = pu.v;
            }

            // ---- PV: O^T += Vt-chunk . P
#pragma unroll
            for (int dt = 0; dt < 8; ++dt) {
#pragma unroll
                for (int c2 = 0; c2 < 2; ++c2) {
                    bf16x8 vf = *reinterpret_cast<const bf16x8*>(
                        &lds_[buf][8192 + (dt * 16 + qi) * 64 + ((c2 * 4 + g) ^ (qi & 7)) * 8]);
                    accO[dt] = __builtin_amdgcn_mfma_f32_16x16x32_bf16(vf, pf[c2], accO[dt], 0, 0, 0);
                }
            }
        }

        if (cn < nch) STAGE_WRITE(buf ^ 1);
        __syncthreads();
        buf ^= 1;
    }

    // ---- write partials
    float srow = s + __shfl_xor(s, 16);
    srow += __shfl_xor(srow, 32);

    const size_t prow = (size_t)bi * 128 + w * 16 + qi;
    if (g == 0) {
        pMS[prow * 2]     = m;
        pMS[prow * 2 + 1] = srow;
    }
#pragma unroll
    for (int dt = 0; dt < 8; ++dt) {
        ushort4v r;
#pragma unroll
        for (int e = 0; e < 4; ++e) r[e] = f2bf(accO[dt][e]);
        *reinterpret_cast<ushort4v*>(&pO[prow * DK + dt * 16 + g * 4]) = r;
    }
#undef STAGE_ISSUE
#undef STAGE_WRITE
}

// ---------------------------------------------------------------------------
// Combine split-K partials (unchanged from r6).
// ---------------------------------------------------------------------------
__global__ __launch_bounds__(256) void attn_combine(
    const unsigned short* __restrict__ pO, const float* __restrict__ pMS,
    float* __restrict__ O)
{
    const int t  = threadIdx.x;
    const int r  = blockIdx.x * 8 + (t >> 5);     // global q row
    const int dq = (t & 31) * 4;

    const int batch = r >> 11;
    const int qbl   = (r >> 7) & 15;
    const int lr    = r & 127;
    const int S     = (qbl == 0) ? 1 : ((qbl + 1) >> 1);
    const int base  = batch * NBLK + (qbl == 0 ? 0 : 1 + (qbl * qbl - (qbl & 1)) / 4);

    float mstar = -1e30f;
    for (int ss = 0; ss < S; ++ss)
        mstar = fmaxf(mstar, pMS[((size_t)(base + ss) * 128 + lr) * 2]);

    float den = 0.f;
    float num[4] = {0.f, 0.f, 0.f, 0.f};
    for (int ss = 0; ss < S; ++ss) {
        const size_t pr = (size_t)(base + ss) * 128 + lr;
        float ms = pMS[pr * 2];
        float sv = pMS[pr * 2 + 1];
        float wgt = __builtin_amdgcn_exp2f(ms - mstar);
        den += wgt * sv;
        ushort4v ov = *reinterpret_cast<const ushort4v*>(&pO[pr * DK + dq]);
#pragma unroll
        for (int e = 0; e < 4; ++e) num[e] += wgt * bf2f(ov[e]);
    }

    const float inv = 1.f / den;
    float4 out;
    out.x = num[0] * inv; out.y = num[1] * inv;
    out.z = num[2] * inv; out.w = num[3] * inv;
    *reinterpret_cast<float4*>(&O[(size_t)r * DK + dq]) = out;
}

extern "C" void kernel_launch(void* const* d_in, const int* in_sizes, int n_in,
                              void* d_out, int out_size, void* d_ws, size_t ws_size,
                              hipStream_t stream) {
    const float* XQ  = (const float*)d_in[0];
    const float* XKV = (const float*)d_in[1];
    const float* Wq  = (const float*)d_in[2];
    const float* bq  = (const float*)d_in[3];
    const float* Wk  = (const float*)d_in[4];
    const float* bk  = (const float*)d_in[5];
    const float* Wv  = (const float*)d_in[6];
    const float* bv  = (const float*)d_in[7];

    unsigned short* Qb = (unsigned short*)d_ws;                 // 2 MB
    unsigned short* Kb = Qb + (size_t)BT * DK;                  // 2 MB
    unsigned short* Vt = Kb + (size_t)BT * DK;                  // 2 MB
    unsigned short* Wt = Vt + (size_t)BT * DK;                  // 0.75 MB
    float*          pMS = (float*)(Wt + (size_t)3 * DK * DM);   // 260*128*2 f32
    unsigned short* pO  = (unsigned short*)(pMS + (size_t)4 * NBLK * 128 * 2); // 8.5 MB

    wt_prep<<<dim3(16, 3), 256, 0, stream>>>(Wq, Wk, Wv, Wt);

    proj_mfma<<<dim3(BT / 64, 3), 256, 0, stream>>>(
        XQ, XKV, Wt, bq, bk, bv, Qb, Kb, Vt);

    attn_kernel<<<dim3(4 * NBLK), 512, 0, stream>>>(Qb, Kb, Vt, pO, pMS);

    attn_combine<<<dim3(BT / 8), 256, 0, stream>>>(pO, pMS, (float*)d_out);
}

// Round 9
// 60.888 us; speedup vs baseline: 1.7949x; 1.7949x over previous
//
#include <hip/hip_runtime.h>
#include <hip/hip_bf16.h>
#include <math.h>

#define BT 8192      // B*T rows total
#define TT 2048      // T
#define DM 1024      // d_model
#define DK 128       // dk == dv
#define NBLK 65      // split-K blocks per batch (sum of S over 16 q-blocks)

typedef __bf16 bf16x8 __attribute__((ext_vector_type(8)));
typedef float  f32x4  __attribute__((ext_vector_type(4)));
typedef unsigned short ushort4v __attribute__((ext_vector_type(4)));
typedef unsigned short ushort8v __attribute__((ext_vector_type(8)));

static __device__ __forceinline__ unsigned short f2bf(float x) {
    union { float f; unsigned u; } v; v.f = x;
    unsigned r = v.u + 0x7fffu + ((v.u >> 16) & 1u);   // RNE
    return (unsigned short)(r >> 16);
}
static __device__ __forceinline__ float bf2f(unsigned short u) {
    union { unsigned u; float f; } v; v.u = (unsigned)u << 16;
    return v.f;
}

// slices for q-block index q (0..15):  S = max(1, (q+1)>>1)   (sum = 65)
__host__ __device__ constexpr int slc_of(int q) { return (q == 0) ? 1 : ((q + 1) >> 1); }
__host__ __device__ constexpr int pfx_of(int q) { return (q == 0) ? 0 : 1 + (q * q - (q & 1)) / 4; }

// 1/sqrt(128) * log2(e): QK^T computed directly in log2 domain
#define QSCALE 0.1275312772629451f

// ---------------------------------------------------------------------------
// Prep: Wt[z][n][k] = bf16(W_z[k][n])
// ---------------------------------------------------------------------------
__global__ __launch_bounds__(256) void wt_prep(
    const float* __restrict__ Wq, const float* __restrict__ Wk,
    const float* __restrict__ Wv, unsigned short* __restrict__ Wt)
{
    const int z = blockIdx.y;
    const float* __restrict__ W = (z == 0) ? Wq : (z == 1 ? Wk : Wv);
    const int k0 = blockIdx.x * 64;

    __shared__ __align__(16) __bf16 T[128][72];
    const int t = threadIdx.x;

#pragma unroll
    for (int jj = 0; jj < 8; ++jj) {
        int c  = jj * 256 + t;
        int k  = c >> 5;
        int n4 = (c & 31) * 4;
        float4 f = *reinterpret_cast<const float4*>(&W[(size_t)(k0 + k) * DK + n4]);
        T[n4 + 0][k] = (__bf16)f.x;
        T[n4 + 1][k] = (__bf16)f.y;
        T[n4 + 2][k] = (__bf16)f.z;
        T[n4 + 3][k] = (__bf16)f.w;
    }
    __syncthreads();

    const int n  = t >> 1;
    const int cb = (t & 1) * 32;
#pragma unroll
    for (int jj = 0; jj < 4; ++jj) {
        *reinterpret_cast<ushort8v*>(&Wt[((size_t)z * DK + n) * DM + k0 + cb + jj * 8]) =
            *reinterpret_cast<const ushort8v*>(&T[n][cb + jj * 8]);
    }
}

// ---------------------------------------------------------------------------
// Projection via MFMA, v4 (r9): global_load_lds double-buffered pipeline.
// Per BK=64 superstep: X-tile (64x64 fp32, 16KB) + W-tile (128x64 bf16, 16KB)
// staged direct-to-LDS via global_load_lds width=16 (no VGPR round trip, the
// compiler cannot sink it — fixes r7's silently-deleted reg prefetch).
// LDS linear, bank spread via pre-swizzled GLOBAL source granule
// (gran ^= row&15 for X, row&7 for W), inverse XOR on the ds_read side.
// One barrier per superstep: its vmcnt(0) drain doubles as load completion.
// 2 x 32KB buffers = 64KB -> 2 blocks/CU (8 waves/CU) for MLP.
// ---------------------------------------------------------------------------
__global__ __launch_bounds__(256) void proj_mfma(
    const float* __restrict__ XQ, const float* __restrict__ XKV,
    const unsigned short* __restrict__ Wt,
    const float* __restrict__ bq, const float* __restrict__ bk,
    const float* __restrict__ bv,
    unsigned short* __restrict__ Qb, unsigned short* __restrict__ Kb,
    unsigned short* __restrict__ Vt)
{
    const int z = blockIdx.y;
    const float* __restrict__ X    = (z == 0) ? XQ : XKV;
    const float* __restrict__ bias = (z == 0) ? bq : (z == 1 ? bk : bv);
    const unsigned short* __restrict__ Wz = Wt + (size_t)z * DK * DM;

    __shared__ __align__(16) unsigned char lds_[2][32768];  // [buf][X 16KB | W 16KB]

    const int t    = threadIdx.x;
    const int lane = t & 63;
    const int wv   = t >> 6;
    const int i16  = lane & 15;
    const int g    = lane >> 4;
    const int m0   = blockIdx.x * 64;

    f32x4 acc[8];
#pragma unroll
    for (int nt = 0; nt < 8; ++nt) acc[nt] = (f32x4){0.f, 0.f, 0.f, 0.f};

    // ---- staging: wave wv issues 4 X-chunks + 4 W-chunks of 1KB each.
    // LDS dest is wave-uniform base (HW adds lane*16); global src is per-lane
    // with the XOR swizzle folded into the source granule.
#define GLOADX(buf_, kk_)                                                      \
    {                                                                          \
        _Pragma("unroll")                                                      \
        for (int j = 0; j < 4; ++j) {                                          \
            const int s    = (wv * 4 + j) * 1024 + lane * 16;                  \
            const int row  = s >> 8;          /* 256B per X row (64 fp32) */   \
            const int gran = (s >> 4) & 15;                                    \
            const float* gp = X + (size_t)(m0 + row) * DM + (kk_) * 64         \
                              + ((gran ^ (row & 15)) << 2);                    \
            __builtin_amdgcn_global_load_lds(                                  \
                (const unsigned int*)gp,                                       \
                (unsigned int*)&lds_[buf_][(wv * 4 + j) * 1024], 16, 0, 0);    \
        }                                                                      \
    }
#define GLOADW(buf_, kk_)                                                      \
    {                                                                          \
        _Pragma("unroll")                                                      \
        for (int j = 0; j < 4; ++j) {                                          \
            const int s    = (wv * 4 + j) * 1024 + lane * 16;                  \
            const int row  = s >> 7;          /* 128B per W row (64 bf16) */   \
            const int gran = (s >> 4) & 7;                                     \
            const unsigned short* gp = Wz + (size_t)row * DM + (kk_) * 64      \
                              + ((gran ^ (row & 7)) << 3);                     \
            __builtin_amdgcn_global_load_lds(                                  \
                (const unsigned int*)gp,                                       \
                (unsigned int*)&lds_[buf_][16384 + (wv * 4 + j) * 1024],       \
                16, 0, 0);                                                     \
        }                                                                      \
    }
#define COMPUTE(buf_)                                                          \
    {                                                                          \
        const float*  Xl = (const float*)&lds_[buf_][0];                       \
        const __bf16* Wl = (const __bf16*)&lds_[buf_][16384];                  \
        _Pragma("unroll")                                                      \
        for (int c = 0; c < 2; ++c) {                                          \
            const int r   = wv * 16 + i16;                                     \
            const int gr0 = 8 * c + 2 * g;                                     \
            float4 x0 = *reinterpret_cast<const float4*>(                      \
                Xl + r * 64 + ((gr0 ^ (r & 15)) << 2));                        \
            float4 x1 = *reinterpret_cast<const float4*>(                      \
                Xl + r * 64 + (((gr0 + 1) ^ (r & 15)) << 2));                  \
            union { __bf16 b[8]; bf16x8 v; } u;                                \
            u.b[0] = (__bf16)x0.x; u.b[1] = (__bf16)x0.y;                      \
            u.b[2] = (__bf16)x0.z; u.b[3] = (__bf16)x0.w;                      \
            u.b[4] = (__bf16)x1.x; u.b[5] = (__bf16)x1.y;                      \
            u.b[6] = (__bf16)x1.z; u.b[7] = (__bf16)x1.w;                      \
            _Pragma("unroll")                                                  \
            for (int nt = 0; nt < 8; ++nt) {                                   \
                const int wr = nt * 16 + i16;                                  \
                bf16x8 wf = *reinterpret_cast<const bf16x8*>(                  \
                    Wl + wr * 64 + (((4 * c + g) ^ (wr & 7)) << 3));           \
                acc[nt] = __builtin_amdgcn_mfma_f32_16x16x32_bf16(             \
                    u.v, wf, acc[nt], 0, 0, 0);                                \
            }                                                                  \
        }                                                                      \
    }

    // prologue: superstep 0 into buf0
    GLOADX(0, 0); GLOADW(0, 0);
    __syncthreads();                      // vmcnt(0) drain -> buf0 ready

#pragma unroll
    for (int kk = 0; kk < 16; kk += 2) {
        GLOADX(1, kk + 1); GLOADW(1, kk + 1);
        COMPUTE(0);                       // superstep kk (even -> buf0)
        __syncthreads();                  // buf1 loads done; buf0 free
        if (kk + 2 < 16) { GLOADX(0, kk + 2); GLOADW(0, kk + 2); }
        COMPUTE(1);                       // superstep kk+1 (odd -> buf1)
        __syncthreads();                  // buf0 loads done; buf1 free
    }
#undef GLOADX
#undef GLOADW
#undef COMPUTE

    if (z == 0) {
#pragma unroll
        for (int nt = 0; nt < 8; ++nt) {
            int n = nt * 16 + i16;
            float bb = bias[n];
#pragma unroll
            for (int r = 0; r < 4; ++r) {
                int mrow = m0 + wv * 16 + g * 4 + r;
                Qb[(size_t)mrow * DK + n] = f2bf((acc[nt][r] + bb) * QSCALE);
            }
        }
    } else if (z == 1) {
#pragma unroll
        for (int nt = 0; nt < 8; ++nt) {
            int n = nt * 16 + i16;
            float bb = bias[n];
#pragma unroll
            for (int r = 0; r < 4; ++r) {
                int mrow = m0 + wv * 16 + g * 4 + r;
                Kb[(size_t)mrow * DK + n] = f2bf(acc[nt][r] + bb);
            }
        }
    } else {
        const int b  = m0 / TT;
        const int t0 = (m0 % TT) + wv * 16 + g * 4;
#pragma unroll
        for (int nt = 0; nt < 8; ++nt) {
            int d = nt * 16 + i16;
            float bb = bias[d];
            ushort4v r;
#pragma unroll
            for (int e = 0; e < 4; ++e) r[e] = f2bf(acc[nt][e] + bb);
            *reinterpret_cast<ushort4v*>(&Vt[((size_t)b * DK + d) * TT + t0]) = r;
        }
    }
}

// ---------------------------------------------------------------------------
// LDS-staged flash attention, proportional split-K (unchanged from r6).
// ---------------------------------------------------------------------------
__global__ __launch_bounds__(512, 2) void attn_kernel(
    const unsigned short* __restrict__ Qb, const unsigned short* __restrict__ Kb,
    const unsigned short* __restrict__ Vt,
    unsigned short* __restrict__ pO, float* __restrict__ pMS)
{
    __shared__ __align__(16) unsigned short lds_[2][16384];   // [buf][K 8192 | V 8192]

    const int t    = threadIdx.x;
    const int lane = t & 63;
    const int w    = t >> 6;
    const int qi   = lane & 15;
    const int g    = lane >> 4;

    // ---- decode block -> (batch, q-block, slice)
    const int bi    = blockIdx.x;
    const int batch = bi / NBLK;
    const int rr    = bi - batch * NBLK;
    int qbl = 0;
#pragma unroll
    for (int i = 1; i < 16; ++i) if (rr >= pfx_of(i)) qbl = i;
    const int slice = rr - (qbl == 0 ? 0 : 1 + (qbl * qbl - (qbl & 1)) / 4);
    const int S     = (qbl == 0) ? 1 : ((qbl + 1) >> 1);
    const int nch   = 2 * qbl + 2;            // 64-key chunks this q-block needs
    const int q0    = qbl * 128;              // batch-local first q row

    const unsigned short* __restrict__ Kbb = Kb + (size_t)batch * TT * DK;
    const unsigned short* __restrict__ Vtb = Vt + (size_t)batch * DK * TT;

    const int qrow  = q0 + w * 16 + qi;       // this lane's q (batch-local)
    const int qminw = q0 + w * 16;            // wave's min q row
    const int qmaxw = q0 + w * 16 + 15;       // wave's max q row

    bf16x8 qf[4];
#pragma unroll
    for (int c = 0; c < 4; ++c)
        qf[c] = *reinterpret_cast<const bf16x8*>(
            &Qb[((size_t)batch * TT + qrow) * DK + c * 32 + g * 8]);

    f32x4 accO[8];
#pragma unroll
    for (int dt = 0; dt < 8; ++dt) accO[dt] = (f32x4){0.f, 0.f, 0.f, 0.f};
    float m = -1e30f, s = 0.f;                // s lane-local, reduced at end

    // ---- staging helpers (wave w<4: K rows, w>=4: Vt rows), 4x16B per lane
    ushort8v sreg[4];
    const int kslot0 = (w & 3) * 256;

#define STAGE_ISSUE(c_)                                                         \
    {                                                                           \
        const int k0s = (c_) * 64;                                              \
        if (w < 4) {                                                            \
            _Pragma("unroll")                                                   \
            for (int i = 0; i < 4; ++i) {                                       \
                int slot = kslot0 + i * 64 + lane;                              \
                int row  = slot >> 4;                                           \
                int colg = (slot & 15) ^ (row & 15);                            \
                sreg[i] = *reinterpret_cast<const ushort8v*>(                   \
                    &Kbb[(size_t)(k0s + row) * DK + colg * 8]);                 \
            }                                                                   \
        } else {                                                                \
            _Pragma("unroll")                                                   \
            for (int i = 0; i < 4; ++i) {                                       \
                int slot = kslot0 + i * 64 + lane;                              \
                int row  = slot >> 3;                                           \
                int colg = (slot & 7) ^ (row & 7);                              \
                sreg[i] = *reinterpret_cast<const ushort8v*>(                   \
                    &Vtb[(size_t)row * TT + k0s + colg * 8]);                   \
            }                                                                   \
        }                                                                       \
    }

#define STAGE_WRITE(buf_)                                                       \
    {                                                                           \
        const int base = (w < 4) ? 0 : 8192;                                    \
        _Pragma("unroll")                                                       \
        for (int i = 0; i < 4; ++i) {                                           \
            int slot = kslot0 + i * 64 + lane;                                  \
            *reinterpret_cast<ushort8v*>(&lds_[buf_][base + slot * 8]) = sreg[i]; \
        }                                                                       \
    }

    // prologue: stage first chunk into buf 0
    STAGE_ISSUE(slice);
    STAGE_WRITE(0);
    __syncthreads();

    int buf = 0;
    for (int c = slice; c < nch; c += S) {
        const int cn = c + S;
        if (cn < nch) STAGE_ISSUE(cn);

        const int k0 = c * 64;
        if (k0 <= qmaxw) {
            // ---- QK^T (S^T): lane(qi,g) col=qi, rows k0+ks*16+g*4+r
            f32x4 accS[4];
#pragma unroll
            for (int ks = 0; ks < 4; ++ks) accS[ks] = (f32x4){0.f, 0.f, 0.f, 0.f};
#pragma unroll
            for (int cc = 0; cc < 4; ++cc) {
#pragma unroll
                for (int ks = 0; ks < 4; ++ks) {
                    bf16x8 kf = *reinterpret_cast<const bf16x8*>(
                        &lds_[buf][(ks * 16 + qi) * 128 + ((cc * 4 + g) ^ qi) * 8]);
                    accS[ks] = __builtin_amdgcn_mfma_f32_16x16x32_bf16(kf, qf[cc], accS[ks], 0, 0, 0);
                }
            }

            // ---- mask + local max (log2 domain already)
            // mask needed unless ALL 64 keys are <= the wave's MIN row
            float xmax = -1e30f;
            if (k0 + 63 > qminw) {
#pragma unroll
                for (int ks = 0; ks < 4; ++ks)
#pragma unroll
                    for (int r = 0; r < 4; ++r) {
                        int k = k0 + ks * 16 + g * 4 + r;
                        float v0 = (k <= qrow) ? accS[ks][r] : -1e30f;
                        accS[ks][r] = v0;
                        xmax = fmaxf(xmax, v0);
                    }
            } else {
#pragma unroll
                for (int ks = 0; ks < 4; ++ks)
#pragma unroll
                    for (int r = 0; r < 4; ++r) xmax = fmaxf(xmax, accS[ks][r]);
            }

            // ---- defer-max
            if (__any(xmax > m + 8.f)) {
                xmax = fmaxf(xmax, __shfl_xor(xmax, 16));
                xmax = fmaxf(xmax, __shfl_xor(xmax, 32));
                float mn   = fmaxf(m, xmax);
                float corr = __builtin_amdgcn_exp2f(m - mn);
                s *= corr;
#pragma unroll
                for (int dt = 0; dt < 8; ++dt)
#pragma unroll
                    for (int e = 0; e < 4; ++e) accO[dt][e] *= corr;
                m = mn;
            }

            // ---- exp2 + pack pairs: pk[ks*2+h] = (p(r=2h), p(r=2h+1))
            unsigned pk[8];
#pragma unroll
            for (int ks = 0; ks < 4; ++ks)
#pragma unroll
                for (int h = 0; h < 2; ++h) {
                    float plo = __builtin_amdgcn_exp2f(accS[ks][h * 2]     - m);
                    float phi = __builtin_amdgcn_exp2f(accS[ks][h * 2 + 1] - m);
                    s += plo + phi;
                    pk[ks * 2 + h] = (unsigned)f2bf(plo) | ((unsigned)f2bf(phi) << 16);
                }

            // ---- redistribute S^T -> PV B-fragments (16 shuffles)
            const int srcl0 = qi + 32 * (g & 1);
            bf16x8 pf[2];
#pragma unroll
            for (int c2 = 0; c2 < 2; ++c2) {
                union { unsigned u[4]; bf16x8 v; } pu;
#pragma unroll
                for (int w4 = 0; w4 < 4; ++w4) {
                    int srcl = srcl0 + 16 * (w4 >> 1);
                    int a = __shfl((int)pk[c2 * 4 + (w4 & 1)],     srcl);
                    int b = __shfl((int)pk[c2 * 4 + 2 + (w4 & 1)], srcl);
                    pu.u[w4] = (g & 2) ? (unsigned)b : (unsigned)a;
                }
                pf[c2] = pu.v;
            }

            // ---- PV: O^T += Vt-chunk . P
#pragma unroll
            for (int dt = 0; dt < 8; ++dt) {
#pragma unroll
                for (int c2 = 0; c2 < 2; ++c2) {
                    bf16x8 vf = *reinterpret_cast<const bf16x8*>(
                        &lds_[buf][8192 + (dt * 16 + qi) * 64 + ((c2 * 4 + g) ^ (qi & 7)) * 8]);
                    accO[dt] = __builtin_amdgcn_mfma_f32_16x16x32_bf16(vf, pf[c2], accO[dt], 0, 0, 0);
                }
            }
        }

        if (cn < nch) STAGE_WRITE(buf ^ 1);
        __syncthreads();
        buf ^= 1;
    }

    // ---- write partials
    float srow = s + __shfl_xor(s, 16);
    srow += __shfl_xor(srow, 32);

    const size_t prow = (size_t)bi * 128 + w * 16 + qi;
    if (g == 0) {
        pMS[prow * 2]     = m;
        pMS[prow * 2 + 1] = srow;
    }
#pragma unroll
    for (int dt = 0; dt < 8; ++dt) {
        ushort4v r;
#pragma unroll
        for (int e = 0; e < 4; ++e) r[e] = f2bf(accO[dt][e]);
        *reinterpret_cast<ushort4v*>(&pO[prow * DK + dt * 16 + g * 4]) = r;
    }
#undef STAGE_ISSUE
#undef STAGE_WRITE
}

// ---------------------------------------------------------------------------
// Combine split-K partials (unchanged from r6).
// ---------------------------------------------------------------------------
__global__ __launch_bounds__(256) void attn_combine(
    const unsigned short* __restrict__ pO, const float* __restrict__ pMS,
    float* __restrict__ O)
{
    const int t  = threadIdx.x;
    const int r  = blockIdx.x * 8 + (t >> 5);     // global q row
    const int dq = (t & 31) * 4;

    const int batch = r >> 11;
    const int qbl   = (r >> 7) & 15;
    const int lr    = r & 127;
    const int S     = (qbl == 0) ? 1 : ((qbl + 1) >> 1);
    const int base  = batch * NBLK + (qbl == 0 ? 0 : 1 + (qbl * qbl - (qbl & 1)) / 4);

    float mstar = -1e30f;
    for (int ss = 0; ss < S; ++ss)
        mstar = fmaxf(mstar, pMS[((size_t)(base + ss) * 128 + lr) * 2]);

    float den = 0.f;
    float num[4] = {0.f, 0.f, 0.f, 0.f};
    for (int ss = 0; ss < S; ++ss) {
        const size_t pr = (size_t)(base + ss) * 128 + lr;
        float ms = pMS[pr * 2];
        float sv = pMS[pr * 2 + 1];
        float wgt = __builtin_amdgcn_exp2f(ms - mstar);
        den += wgt * sv;
        ushort4v ov = *reinterpret_cast<const ushort4v*>(&pO[pr * DK + dq]);
#pragma unroll
        for (int e = 0; e < 4; ++e) num[e] += wgt * bf2f(ov[e]);
    }

    const float inv = 1.f / den;
    float4 out;
    out.x = num[0] * inv; out.y = num[1] * inv;
    out.z = num[2] * inv; out.w = num[3] * inv;
    *reinterpret_cast<float4*>(&O[(size_t)r * DK + dq]) = out;
}

extern "C" void kernel_launch(void* const* d_in, const int* in_sizes, int n_in,
                              void* d_out, int out_size, void* d_ws, size_t ws_size,
                              hipStream_t stream) {
    const float* XQ  = (const float*)d_in[0];
    const float* XKV = (const float*)d_in[1];
    const float* Wq  = (const float*)d_in[2];
    const float* bq  = (const float*)d_in[3];
    const float* Wk  = (const float*)d_in[4];
    const float* bk  = (const float*)d_in[5];
    const float* Wv  = (const float*)d_in[6];
    const float* bv  = (const float*)d_in[7];

    unsigned short* Qb = (unsigned short*)d_ws;                 // 2 MB
    unsigned short* Kb = Qb + (size_t)BT * DK;                  // 2 MB
    unsigned short* Vt = Kb + (size_t)BT * DK;                  // 2 MB
    unsigned short* Wt = Vt + (size_t)BT * DK;                  // 0.75 MB
    float*          pMS = (float*)(Wt + (size_t)3 * DK * DM);   // 260*128*2 f32
    unsigned short* pO  = (unsigned short*)(pMS + (size_t)4 * NBLK * 128 * 2); // 8.5 MB

    wt_prep<<<dim3(16, 3), 256, 0, stream>>>(Wq, Wk, Wv, Wt);

    proj_mfma<<<dim3(BT / 64, 3), 256, 0, stream>>>(
        XQ, XKV, Wt, bq, bk, bv, Qb, Kb, Vt);

    attn_kernel<<<dim3(4 * NBLK), 512, 0, stream>>>(Qb, Kb, Vt, pO, pMS);

    attn_combine<<<dim3(BT / 8), 256, 0, stream>>>(pO, pMS, (float*)d_out);
}

// Round 10
// 55.971 us; speedup vs baseline: 1.9526x; 1.0879x over previous
//
#include <hip/hip_runtime.h>
#include <hip/hip_bf16.h>
#include <math.h>

#define BT 8192      // B*T rows total
#define TT 2048      // T
#define DM 1024      // d_model
#define DK 128       // dk == dv
#define NBLK 65      // split-K blocks per batch (sum of S over 16 q-blocks)

typedef __bf16 bf16x8 __attribute__((ext_vector_type(8)));
typedef float  f32x4  __attribute__((ext_vector_type(4)));
typedef unsigned short ushort4v __attribute__((ext_vector_type(4)));
typedef unsigned short ushort8v __attribute__((ext_vector_type(8)));

static __device__ __forceinline__ unsigned short f2bf(float x) {
    union { float f; unsigned u; } v; v.f = x;
    unsigned r = v.u + 0x7fffu + ((v.u >> 16) & 1u);   // RNE
    return (unsigned short)(r >> 16);
}
static __device__ __forceinline__ float bf2f(unsigned short u) {
    union { unsigned u; float f; } v; v.u = (unsigned)u << 16;
    return v.f;
}

// slices for q-block index q (0..15):  S = max(1, (q+1)>>1)   (sum = 65)
__host__ __device__ constexpr int slc_of(int q) { return (q == 0) ? 1 : ((q + 1) >> 1); }
__host__ __device__ constexpr int pfx_of(int q) { return (q == 0) ? 0 : 1 + (q * q - (q & 1)) / 4; }

// 1/sqrt(128) * log2(e): QK^T computed directly in log2 domain
#define QSCALE 0.1275312772629451f

// ---------------------------------------------------------------------------
// Prep: Wt[z][n][k] = bf16(W_z[k][n])
// ---------------------------------------------------------------------------
__global__ __launch_bounds__(256) void wt_prep(
    const float* __restrict__ Wq, const float* __restrict__ Wk,
    const float* __restrict__ Wv, unsigned short* __restrict__ Wt)
{
    const int z = blockIdx.y;
    const float* __restrict__ W = (z == 0) ? Wq : (z == 1 ? Wk : Wv);
    const int k0 = blockIdx.x * 64;

    __shared__ __align__(16) __bf16 T[128][72];
    const int t = threadIdx.x;

#pragma unroll
    for (int jj = 0; jj < 8; ++jj) {
        int c  = jj * 256 + t;
        int k  = c >> 5;
        int n4 = (c & 31) * 4;
        float4 f = *reinterpret_cast<const float4*>(&W[(size_t)(k0 + k) * DK + n4]);
        T[n4 + 0][k] = (__bf16)f.x;
        T[n4 + 1][k] = (__bf16)f.y;
        T[n4 + 2][k] = (__bf16)f.z;
        T[n4 + 3][k] = (__bf16)f.w;
    }
    __syncthreads();

    const int n  = t >> 1;
    const int cb = (t & 1) * 32;
#pragma unroll
    for (int jj = 0; jj < 4; ++jj) {
        *reinterpret_cast<ushort8v*>(&Wt[((size_t)z * DK + n) * DM + k0 + cb + jj * 8]) =
            *reinterpret_cast<const ushort8v*>(&T[n][cb + jj * 8]);
    }
}

// ---------------------------------------------------------------------------
// Projection via MFMA, v6 (r10): same gload_lds double-buffer pipeline as r9
// but M-tile 32 (wave grid 2Mx2N) -> 24KB buffers, 48KB LDS, 3 blocks/CU,
// grid 768 = 3 blocks on every CU co-resident. The r9 counters showed the
// limiter was CU-level concurrency (1.15 blocks/CU, memory pipe duty-cycled
// by the per-superstep barrier drain); 3 desynced blocks/CU keep it fed.
// ---------------------------------------------------------------------------
__global__ __launch_bounds__(256) void proj_mfma(
    const float* __restrict__ XQ, const float* __restrict__ XKV,
    const unsigned short* __restrict__ Wt,
    const float* __restrict__ bq, const float* __restrict__ bk,
    const float* __restrict__ bv,
    unsigned short* __restrict__ Qb, unsigned short* __restrict__ Kb,
    unsigned short* __restrict__ Vt)
{
    const int z = blockIdx.y;
    const float* __restrict__ X    = (z == 0) ? XQ : XKV;
    const float* __restrict__ bias = (z == 0) ? bq : (z == 1 ? bk : bv);
    const unsigned short* __restrict__ Wz = Wt + (size_t)z * DK * DM;

    __shared__ __align__(16) unsigned char lds_[2][24576];  // [buf][X 8KB | W 16KB]

    const int t    = threadIdx.x;
    const int lane = t & 63;
    const int wv   = t >> 6;
    const int i16  = lane & 15;
    const int g    = lane >> 4;
    const int wm   = wv >> 1;         // wave row-tile (0..1)
    const int wn   = wv & 1;          // wave col-tile (0..1)
    const int m0   = blockIdx.x * 32;

    f32x4 acc[4];
#pragma unroll
    for (int nt = 0; nt < 4; ++nt) acc[nt] = (f32x4){0.f, 0.f, 0.f, 0.f};

    // ---- staging: per superstep, X 8KB (2 instr/wave) + W 16KB (4 instr/wave)
    // LDS linear; global source pre-swizzled (gran ^= row&15 / row&7);
    // inverse XOR on the ds_read side.  All banks verified 2-way max (free).
#define GLOADX(buf_, kk_)                                                      \
    {                                                                          \
        _Pragma("unroll")                                                      \
        for (int j = 0; j < 2; ++j) {                                          \
            const int s    = (wv * 2 + j) * 1024 + lane * 16;                  \
            const int row  = s >> 8;          /* 256B per X row (64 fp32) */   \
            const int gran = (s >> 4) & 15;                                    \
            const float* gp = X + (size_t)(m0 + row) * DM + (kk_) * 64         \
                              + ((gran ^ (row & 15)) << 2);                    \
            __builtin_amdgcn_global_load_lds(                                  \
                (const unsigned int*)gp,                                       \
                (unsigned int*)&lds_[buf_][(wv * 2 + j) * 1024], 16, 0, 0);    \
        }                                                                      \
    }
#define GLOADW(buf_, kk_)                                                      \
    {                                                                          \
        _Pragma("unroll")                                                      \
        for (int j = 0; j < 4; ++j) {                                          \
            const int s    = (wv * 4 + j) * 1024 + lane * 16;                  \
            const int row  = s >> 7;          /* 128B per W row (64 bf16) */   \
            const int gran = (s >> 4) & 7;                                     \
            const unsigned short* gp = Wz + (size_t)row * DM + (kk_) * 64      \
                              + ((gran ^ (row & 7)) << 3);                     \
            __builtin_amdgcn_global_load_lds(                                  \
                (const unsigned int*)gp,                                       \
                (unsigned int*)&lds_[buf_][8192 + (wv * 4 + j) * 1024],        \
                16, 0, 0);                                                     \
        }                                                                      \
    }
#define COMPUTE(buf_)                                                          \
    {                                                                          \
        const float*  Xl = (const float*)&lds_[buf_][0];                       \
        const __bf16* Wl = (const __bf16*)&lds_[buf_][8192];                   \
        _Pragma("unroll")                                                      \
        for (int c = 0; c < 2; ++c) {                                          \
            const int r   = wm * 16 + i16;                                     \
            const int gr0 = 8 * c + 2 * g;                                     \
            float4 x0 = *reinterpret_cast<const float4*>(                      \
                Xl + r * 64 + ((gr0 ^ (r & 15)) << 2));                        \
            float4 x1 = *reinterpret_cast<const float4*>(                      \
                Xl + r * 64 + (((gr0 + 1) ^ (r & 15)) << 2));                  \
            union { __bf16 b[8]; bf16x8 v; } u;                                \
            u.b[0] = (__bf16)x0.x; u.b[1] = (__bf16)x0.y;                      \
            u.b[2] = (__bf16)x0.z; u.b[3] = (__bf16)x0.w;                      \
            u.b[4] = (__bf16)x1.x; u.b[5] = (__bf16)x1.y;                      \
            u.b[6] = (__bf16)x1.z; u.b[7] = (__bf16)x1.w;                      \
            _Pragma("unroll")                                                  \
            for (int nt = 0; nt < 4; ++nt) {                                   \
                const int wr = wn * 64 + nt * 16 + i16;                        \
                bf16x8 wf = *reinterpret_cast<const bf16x8*>(                  \
                    Wl + wr * 64 + (((4 * c + g) ^ (wr & 7)) << 3));           \
                acc[nt] = __builtin_amdgcn_mfma_f32_16x16x32_bf16(             \
                    u.v, wf, acc[nt], 0, 0, 0);                                \
            }                                                                  \
        }                                                                      \
    }

    // prologue: superstep 0 into buf0
    GLOADX(0, 0); GLOADW(0, 0);
    __syncthreads();                      // vmcnt(0) drain -> buf0 ready

#pragma unroll
    for (int kk = 0; kk < 16; kk += 2) {
        GLOADX(1, kk + 1); GLOADW(1, kk + 1);
        COMPUTE(0);                       // superstep kk (even -> buf0)
        __syncthreads();                  // buf1 loads done; buf0 free
        if (kk + 2 < 16) { GLOADX(0, kk + 2); GLOADW(0, kk + 2); }
        COMPUTE(1);                       // superstep kk+1 (odd -> buf1)
        __syncthreads();                  // buf0 loads done; buf1 free
    }
#undef GLOADX
#undef GLOADW
#undef COMPUTE

    if (z == 0) {
#pragma unroll
        for (int nt = 0; nt < 4; ++nt) {
            int n = wn * 64 + nt * 16 + i16;
            float bb = bias[n];
#pragma unroll
            for (int r = 0; r < 4; ++r) {
                int mrow = m0 + wm * 16 + g * 4 + r;
                Qb[(size_t)mrow * DK + n] = f2bf((acc[nt][r] + bb) * QSCALE);
            }
        }
    } else if (z == 1) {
#pragma unroll
        for (int nt = 0; nt < 4; ++nt) {
            int n = wn * 64 + nt * 16 + i16;
            float bb = bias[n];
#pragma unroll
            for (int r = 0; r < 4; ++r) {
                int mrow = m0 + wm * 16 + g * 4 + r;
                Kb[(size_t)mrow * DK + n] = f2bf(acc[nt][r] + bb);
            }
        }
    } else {
        const int b  = m0 / TT;
        const int t0 = (m0 % TT) + wm * 16 + g * 4;
#pragma unroll
        for (int nt = 0; nt < 4; ++nt) {
            int d = wn * 64 + nt * 16 + i16;
            float bb = bias[d];
            ushort4v r;
#pragma unroll
            for (int e = 0; e < 4; ++e) r[e] = f2bf(acc[nt][e] + bb);
            *reinterpret_cast<ushort4v*>(&Vt[((size_t)b * DK + d) * TT + t0]) = r;
        }
    }
}

// ---------------------------------------------------------------------------
// LDS-staged flash attention, proportional split-K (unchanged from r6).
// ---------------------------------------------------------------------------
__global__ __launch_bounds__(512, 2) void attn_kernel(
    const unsigned short* __restrict__ Qb, const unsigned short* __restrict__ Kb,
    const unsigned short* __restrict__ Vt,
    unsigned short* __restrict__ pO, float* __restrict__ pMS)
{
    __shared__ __align__(16) unsigned short lds_[2][16384];   // [buf][K 8192 | V 8192]

    const int t    = threadIdx.x;
    const int lane = t & 63;
    const int w    = t >> 6;
    const int qi   = lane & 15;
    const int g    = lane >> 4;

    // ---- decode block -> (batch, q-block, slice)
    const int bi    = blockIdx.x;
    const int batch = bi / NBLK;
    const int rr    = bi - batch * NBLK;
    int qbl = 0;
#pragma unroll
    for (int i = 1; i < 16; ++i) if (rr >= pfx_of(i)) qbl = i;
    const int slice = rr - (qbl == 0 ? 0 : 1 + (qbl * qbl - (qbl & 1)) / 4);
    const int S     = (qbl == 0) ? 1 : ((qbl + 1) >> 1);
    const int nch   = 2 * qbl + 2;            // 64-key chunks this q-block needs
    const int q0    = qbl * 128;              // batch-local first q row

    const unsigned short* __restrict__ Kbb = Kb + (size_t)batch * TT * DK;
    const unsigned short* __restrict__ Vtb = Vt + (size_t)batch * DK * TT;

    const int qrow  = q0 + w * 16 + qi;       // this lane's q (batch-local)
    const int qminw = q0 + w * 16;            // wave's min q row
    const int qmaxw = q0 + w * 16 + 15;       // wave's max q row

    bf16x8 qf[4];
#pragma unroll
    for (int c = 0; c < 4; ++c)
        qf[c] = *reinterpret_cast<const bf16x8*>(
            &Qb[((size_t)batch * TT + qrow) * DK + c * 32 + g * 8]);

    f32x4 accO[8];
#pragma unroll
    for (int dt = 0; dt < 8; ++dt) accO[dt] = (f32x4){0.f, 0.f, 0.f, 0.f};
    float m = -1e30f, s = 0.f;                // s lane-local, reduced at end

    // ---- staging helpers (wave w<4: K rows, w>=4: Vt rows), 4x16B per lane
    ushort8v sreg[4];
    const int kslot0 = (w & 3) * 256;

#define STAGE_ISSUE(c_)                                                         \
    {                                                                           \
        const int k0s = (c_) * 64;                                              \
        if (w < 4) {                                                            \
            _Pragma("unroll")                                                   \
            for (int i = 0; i < 4; ++i) {                                       \
                int slot = kslot0 + i * 64 + lane;                              \
                int row  = slot >> 4;                                           \
                int colg = (slot & 15) ^ (row & 15);                            \
                sreg[i] = *reinterpret_cast<const ushort8v*>(                   \
                    &Kbb[(size_t)(k0s + row) * DK + colg * 8]);                 \
            }                                                                   \
        } else {                                                                \
            _Pragma("unroll")                                                   \
            for (int i = 0; i < 4; ++i) {                                       \
                int slot = kslot0 + i * 64 + lane;                              \
                int row  = slot >> 3;                                           \
                int colg = (slot & 7) ^ (row & 7);                              \
                sreg[i] = *reinterpret_cast<const ushort8v*>(                   \
                    &Vtb[(size_t)row * TT + k0s + colg * 8]);                   \
            }                                                                   \
        }                                                                       \
    }

#define STAGE_WRITE(buf_)                                                       \
    {                                                                           \
        const int base = (w < 4) ? 0 : 8192;                                    \
        _Pragma("unroll")                                                       \
        for (int i = 0; i < 4; ++i) {                                           \
            int slot = kslot0 + i * 64 + lane;                                  \
            *reinterpret_cast<ushort8v*>(&lds_[buf_][base + slot * 8]) = sreg[i]; \
        }                                                                       \
    }

    // prologue: stage first chunk into buf 0
    STAGE_ISSUE(slice);
    STAGE_WRITE(0);
    __syncthreads();

    int buf = 0;
    for (int c = slice; c < nch; c += S) {
        const int cn = c + S;
        if (cn < nch) STAGE_ISSUE(cn);

        const int k0 = c * 64;
        if (k0 <= qmaxw) {
            // ---- QK^T (S^T): lane(qi,g) col=qi, rows k0+ks*16+g*4+r
            f32x4 accS[4];
#pragma unroll
            for (int ks = 0; ks < 4; ++ks) accS[ks] = (f32x4){0.f, 0.f, 0.f, 0.f};
#pragma unroll
            for (int cc = 0; cc < 4; ++cc) {
#pragma unroll
                for (int ks = 0; ks < 4; ++ks) {
                    bf16x8 kf = *reinterpret_cast<const bf16x8*>(
                        &lds_[buf][(ks * 16 + qi) * 128 + ((cc * 4 + g) ^ qi) * 8]);
                    accS[ks] = __builtin_amdgcn_mfma_f32_16x16x32_bf16(kf, qf[cc], accS[ks], 0, 0, 0);
                }
            }

            // ---- mask + local max (log2 domain already)
            // mask needed unless ALL 64 keys are <= the wave's MIN row
            float xmax = -1e30f;
            if (k0 + 63 > qminw) {
#pragma unroll
                for (int ks = 0; ks < 4; ++ks)
#pragma unroll
                    for (int r = 0; r < 4; ++r) {
                        int k = k0 + ks * 16 + g * 4 + r;
                        float v0 = (k <= qrow) ? accS[ks][r] : -1e30f;
                        accS[ks][r] = v0;
                        xmax = fmaxf(xmax, v0);
                    }
            } else {
#pragma unroll
                for (int ks = 0; ks < 4; ++ks)
#pragma unroll
                    for (int r = 0; r < 4; ++r) xmax = fmaxf(xmax, accS[ks][r]);
            }

            // ---- defer-max
            if (__any(xmax > m + 8.f)) {
                xmax = fmaxf(xmax, __shfl_xor(xmax, 16));
                xmax = fmaxf(xmax, __shfl_xor(xmax, 32));
                float mn   = fmaxf(m, xmax);
                float corr = __builtin_amdgcn_exp2f(m - mn);
                s *= corr;
#pragma unroll
                for (int dt = 0; dt < 8; ++dt)
#pragma unroll
                    for (int e = 0; e < 4; ++e) accO[dt][e] *= corr;
                m = mn;
            }

            // ---- exp2 + pack pairs: pk[ks*2+h] = (p(r=2h), p(r=2h+1))
            unsigned pk[8];
#pragma unroll
            for (int ks = 0; ks < 4; ++ks)
#pragma unroll
                for (int h = 0; h < 2; ++h) {
                    float plo = __builtin_amdgcn_exp2f(accS[ks][h * 2]     - m);
                    float phi = __builtin_amdgcn_exp2f(accS[ks][h * 2 + 1] - m);
                    s += plo + phi;
                    pk[ks * 2 + h] = (unsigned)f2bf(plo) | ((unsigned)f2bf(phi) << 16);
                }

            // ---- redistribute S^T -> PV B-fragments (16 shuffles)
            const int srcl0 = qi + 32 * (g & 1);
            bf16x8 pf[2];
#pragma unroll
            for (int c2 = 0; c2 < 2; ++c2) {
                union { unsigned u[4]; bf16x8 v; } pu;
#pragma unroll
                for (int w4 = 0; w4 < 4; ++w4) {
                    int srcl = srcl0 + 16 * (w4 >> 1);
                    int a = __shfl((int)pk[c2 * 4 + (w4 & 1)],     srcl);
                    int b = __shfl((int)pk[c2 * 4 + 2 + (w4 & 1)], srcl);
                    pu.u[w4] = (g & 2) ? (unsigned)b : (unsigned)a;
                }
                pf[c2] = pu.v;
            }

            // ---- PV: O^T += Vt-chunk . P
#pragma unroll
            for (int dt = 0; dt < 8; ++dt) {
#pragma unroll
                for (int c2 = 0; c2 < 2; ++c2) {
                    bf16x8 vf = *reinterpret_cast<const bf16x8*>(
                        &lds_[buf][8192 + (dt * 16 + qi) * 64 + ((c2 * 4 + g) ^ (qi & 7)) * 8]);
                    accO[dt] = __builtin_amdgcn_mfma_f32_16x16x32_bf16(vf, pf[c2], accO[dt], 0, 0, 0);
                }
            }
        }

        if (cn < nch) STAGE_WRITE(buf ^ 1);
        __syncthreads();
        buf ^= 1;
    }

    // ---- write partials
    float srow = s + __shfl_xor(s, 16);
    srow += __shfl_xor(srow, 32);

    const size_t prow = (size_t)bi * 128 + w * 16 + qi;
    if (g == 0) {
        pMS[prow * 2]     = m;
        pMS[prow * 2 + 1] = srow;
    }
#pragma unroll
    for (int dt = 0; dt < 8; ++dt) {
        ushort4v r;
#pragma unroll
        for (int e = 0; e < 4; ++e) r[e] = f2bf(accO[dt][e]);
        *reinterpret_cast<ushort4v*>(&pO[prow * DK + dt * 16 + g * 4]) = r;
    }
#undef STAGE_ISSUE
#undef STAGE_WRITE
}

// ---------------------------------------------------------------------------
// Combine split-K partials (unchanged from r6).
// ---------------------------------------------------------------------------
__global__ __launch_bounds__(256) void attn_combine(
    const unsigned short* __restrict__ pO, const float* __restrict__ pMS,
    float* __restrict__ O)
{
    const int t  = threadIdx.x;
    const int r  = blockIdx.x * 8 + (t >> 5);     // global q row
    const int dq = (t & 31) * 4;

    const int batch = r >> 11;
    const int qbl   = (r >> 7) & 15;
    const int lr    = r & 127;
    const int S     = (qbl == 0) ? 1 : ((qbl + 1) >> 1);
    const int base  = batch * NBLK + (qbl == 0 ? 0 : 1 + (qbl * qbl - (qbl & 1)) / 4);

    float mstar = -1e30f;
    for (int ss = 0; ss < S; ++ss)
        mstar = fmaxf(mstar, pMS[((size_t)(base + ss) * 128 + lr) * 2]);

    float den = 0.f;
    float num[4] = {0.f, 0.f, 0.f, 0.f};
    for (int ss = 0; ss < S; ++ss) {
        const size_t pr = (size_t)(base + ss) * 128 + lr;
        float ms = pMS[pr * 2];
        float sv = pMS[pr * 2 + 1];
        float wgt = __builtin_amdgcn_exp2f(ms - mstar);
        den += wgt * sv;
        ushort4v ov = *reinterpret_cast<const ushort4v*>(&pO[pr * DK + dq]);
#pragma unroll
        for (int e = 0; e < 4; ++e) num[e] += wgt * bf2f(ov[e]);
    }

    const float inv = 1.f / den;
    float4 out;
    out.x = num[0] * inv; out.y = num[1] * inv;
    out.z = num[2] * inv; out.w = num[3] * inv;
    *reinterpret_cast<float4*>(&O[(size_t)r * DK + dq]) = out;
}

extern "C" void kernel_launch(void* const* d_in, const int* in_sizes, int n_in,
                              void* d_out, int out_size, void* d_ws, size_t ws_size,
                              hipStream_t stream) {
    const float* XQ  = (const float*)d_in[0];
    const float* XKV = (const float*)d_in[1];
    const float* Wq  = (const float*)d_in[2];
    const float* bq  = (const float*)d_in[3];
    const float* Wk  = (const float*)d_in[4];
    const float* bk  = (const float*)d_in[5];
    const float* Wv  = (const float*)d_in[6];
    const float* bv  = (const float*)d_in[7];

    unsigned short* Qb = (unsigned short*)d_ws;                 // 2 MB
    unsigned short* Kb = Qb + (size_t)BT * DK;                  // 2 MB
    unsigned short* Vt = Kb + (size_t)BT * DK;                  // 2 MB
    unsigned short* Wt = Vt + (size_t)BT * DK;                  // 0.75 MB
    float*          pMS = (float*)(Wt + (size_t)3 * DK * DM);   // 260*128*2 f32
    unsigned short* pO  = (unsigned short*)(pMS + (size_t)4 * NBLK * 128 * 2); // 8.5 MB

    wt_prep<<<dim3(16, 3), 256, 0, stream>>>(Wq, Wk, Wv, Wt);

    proj_mfma<<<dim3(BT / 32, 3), 256, 0, stream>>>(
        XQ, XKV, Wt, bq, bk, bv, Qb, Kb, Vt);

    attn_kernel<<<dim3(4 * NBLK), 512, 0, stream>>>(Qb, Kb, Vt, pO, pMS);

    attn_combine<<<dim3(BT / 8), 256, 0, stream>>>(pO, pMS, (float*)d_out);
}